// Round 5
// baseline (2125.663 us; speedup 1.0000x reference)
//
#include <hip/hip_runtime.h>
#include <hip/hip_bf16.h>

typedef __hip_bfloat16 bf16;
using v8s   = __attribute__((ext_vector_type(8))) short;
using f32x4 = __attribute__((ext_vector_type(4))) float;

#define DI __device__ __forceinline__

DI float gelu_f(float x) { return 0.5f * x * (1.f + erff(x * 0.70710678118654752f)); }

DI void g2lds16(const bf16* g, bf16* l) {
  __builtin_amdgcn_global_load_lds((const __attribute__((address_space(1))) void*)g,
                                   (__attribute__((address_space(3))) void*)l, 16, 0, 0);
}

// ---------------- block reduction helpers (256 threads, 4 waves) ----------------
DI float block_sum(float v, float* red, int tid) {
#pragma unroll
  for (int o = 32; o > 0; o >>= 1) v += __shfl_down(v, o);
  __syncthreads();
  if ((tid & 63) == 0) red[tid >> 6] = v;
  __syncthreads();
  return red[0] + red[1] + red[2] + red[3];
}
DI float block_max(float v, float* red, int tid) {
#pragma unroll
  for (int o = 32; o > 0; o >>= 1) v = fmaxf(v, __shfl_down(v, o));
  __syncthreads();
  if ((tid & 63) == 0) red[tid >> 6] = v;
  __syncthreads();
  return fmaxf(fmaxf(red[0], red[1]), fmaxf(red[2], red[3]));
}

// ---------------- weight prep ----------------
__global__ __launch_bounds__(256)
void tconv(const float* __restrict__ in, bf16* __restrict__ out,
           int R, int C, long inStrideZ, long outStrideL, long outStrideH, int zmod) {
  __shared__ float tile[32][33];
  int z = blockIdx.z;
  int lz = z / zmod, hz = z - lz * zmod;
  in  += (long)z * inStrideZ;
  out += (long)lz * outStrideL + (long)hz * outStrideH;
  int cb = blockIdx.x * 32, rb = blockIdx.y * 32;
  int tx = threadIdx.x & 31, ty = threadIdx.x >> 5;  // 32x8
#pragma unroll
  for (int i = 0; i < 32; i += 8)
    tile[ty + i][tx] = in[(long)(rb + ty + i) * C + cb + tx];
  __syncthreads();
#pragma unroll
  for (int i = 0; i < 32; i += 8)
    out[(long)(cb + ty + i) * R + rb + tx] = __float2bfloat16(tile[tx][ty + i]);
}

__global__ __launch_bounds__(256)
void prep_cw(const float* __restrict__ wsrc, bf16* __restrict__ o, int IC, int KT) {
  int idx = blockIdx.x * 256 + threadIdx.x;
  int oc = idx / KT, kp = idx - oc * KT;
  float v = 0.f;
  if (kp < IC * 3) {
    int kk = kp / IC, ic = kp - kk * IC;
    v = wsrc[(oc * IC + ic) * 3 + kk];
  }
  o[idx] = __float2bfloat16(v);
}

__global__ __launch_bounds__(256)
void prep_bias(const float* __restrict__ bq, const float* __restrict__ bk,
               const float* __restrict__ bv, float* __restrict__ o) {
  int idx = blockIdx.x * 256 + threadIdx.x;  // 6*2304
  int l = idx / 2304, n = idx - l * 2304;
  int which = n / 768, r = n - which * 768;
  const float* src = which == 0 ? bq : (which == 1 ? bk : bv);
  o[idx] = src[l * 768 + r];
}

// pad-repack head layer-2 weights: hw2 [3072][527] -> hw2p [3072][640] (zero pad)
__global__ __launch_bounds__(256)
void prep_hw2(const float* __restrict__ hw2, const float* __restrict__ hb2,
              float* __restrict__ hw2p, float* __restrict__ hb2p) {
  int idx = blockIdx.x * 256 + threadIdx.x;  // 3072*640
  int e = idx / 640, c = idx - e * 640;
  hw2p[idx] = c < 527 ? hw2[(long)e * 527 + c] : 0.f;
  if (idx < 640) hb2p[idx] = idx < 527 ? hb2[idx] : 0.f;
}

// ---------------- im2col ----------------
__global__ __launch_bounds__(256)
void im2col1(const float* __restrict__ x, bf16* __restrict__ out) {
  int idx = blockIdx.x * 256 + threadIdx.x;  // 8192*256
  int m = idx >> 8, kp = idx & 255;
  float v = 0.f;
  if (kp < 240) {
    int kk = kp / 80, ic = kp - kk * 80;
    int t = (m & 2047) + kk - 1;
    int b = m >> 11;
    if ((unsigned)t < 2048u) v = x[((long)(b * 80 + ic) << 11) + t];
  }
  out[idx] = __float2bfloat16(v);
}

__global__ __launch_bounds__(256)
void im2col2(const bf16* __restrict__ y, bf16* __restrict__ out) {
  int idx = blockIdx.x * 256 + threadIdx.x;  // 4096*2304
  int m = idx / 2304, kp = idx - m * 2304;
  int kk = kp / 768, ic = kp - kk * 768;
  int t = 2 * (m & 1023) + kk - 1;
  bf16 v = __float2bfloat16(0.f);
  if ((unsigned)t < 2048u) v = y[((long)(m >> 10) * 2048 + t) * 768 + ic];
  out[idx] = v;
}

// ---------------- GEMM: C[m][n] = sum_k A[m][k]*B[n][k]  (both bf16, K%64==0) ----------------
// 2-phase double-buffered K-loop: prefetch tile t+1 via global_load_lds BEFORE
// computing tile t; single vmcnt(0)+barrier (from __syncthreads) per iteration.
enum { EPI_GELU_BF16, EPI_CONV2, EPI_QKV, EPI_SBF, EPI_CC, EPI_BIAS_F32, EPI_RELU_BF16 };

struct GP {
  const bf16* A; const bf16* B; const float* bias;
  bf16* Ob; float* Of; const float* aux;
  int M, N, K; long sA, sB, sC; int zoff;
};

template<int BM, int BN, int WM, int WN, int EPI>
__global__ __launch_bounds__(256)
void gemm_bt(GP p) {
  constexpr int FM = BM / WM / 16, FN = BN / WN / 16;
  __shared__ __align__(16) bf16 As0[BM * 64], Bs0[BN * 64];
  __shared__ __align__(16) bf16 As1[BM * 64], Bs1[BN * 64];
  const int tid = threadIdx.x;
  const int lane = tid & 63, wid = tid >> 6;
  const int wr = wid / WN, wc = wid - wr * WN;
  const int row0 = wr * (BM / WM), col0 = wc * (BN / WN);
  const int lr = lane & 15, lk = (lane >> 4) * 8;
  const int lrow = lane >> 3, lcol = (lane & 7) * 8;  // staging: lane -> (row in chunk, col)
  const int z = blockIdx.z;
  const bf16* Ab = p.A + (long)z * p.sA + (long)blockIdx.x * BM * p.K;
  const bf16* Bb = p.B + (long)z * p.sB + (long)blockIdx.y * BN * p.K;
  f32x4 acc[FM][FN] = {};

  auto stage = [&](bf16* As, bf16* Bs, int kt) {
#pragma unroll
    for (int i = 0; i < BM / 32; ++i) {
      const int c = wid + i * 4;  // chunk of 8 rows (1KB)
      g2lds16(&Ab[(long)(c * 8 + lrow) * p.K + kt + lcol], &As[c << 9]);
    }
#pragma unroll
    for (int i = 0; i < BN / 32; ++i) {
      const int c = wid + i * 4;
      g2lds16(&Bb[(long)(c * 8 + lrow) * p.K + kt + lcol], &Bs[c << 9]);
    }
  };

  auto compute = [&](const bf16* As, const bf16* Bs) {
#pragma unroll
    for (int ks = 0; ks < 2; ++ks) {
      v8s af[FM], bf_[FN];
#pragma unroll
      for (int mi = 0; mi < FM; ++mi)
        af[mi] = *(const v8s*)&As[(row0 + mi * 16 + lr) * 64 + ks * 32 + lk];
#pragma unroll
      for (int ni = 0; ni < FN; ++ni)
        bf_[ni] = *(const v8s*)&Bs[(col0 + ni * 16 + lr) * 64 + ks * 32 + lk];
#pragma unroll
      for (int mi = 0; mi < FM; ++mi)
#pragma unroll
        for (int ni = 0; ni < FN; ++ni)
          acc[mi][ni] = __builtin_amdgcn_mfma_f32_16x16x32_bf16(af[mi], bf_[ni], acc[mi][ni], 0, 0, 0);
    }
  };

  stage(As0, Bs0, 0);
  __syncthreads();
  int kt = 0;
  while (true) {
    if (kt + 64 < p.K) stage(As1, Bs1, kt + 64);
    compute(As0, Bs0);
    __syncthreads();
    kt += 64;
    if (kt >= p.K) break;
    if (kt + 64 < p.K) stage(As0, Bs0, kt + 64);
    compute(As1, Bs1);
    __syncthreads();
    kt += 64;
    if (kt >= p.K) break;
  }

  // epilogue; D: row=(lane>>4)*4+r, col=lane&15
#pragma unroll
  for (int mi = 0; mi < FM; ++mi) {
#pragma unroll
    for (int ni = 0; ni < FN; ++ni) {
#pragma unroll
      for (int r = 0; r < 4; ++r) {
        float v = acc[mi][ni][r];
        const int m = blockIdx.x * BM + row0 + mi * 16 + (lane >> 4) * 4 + r;
        const int n = blockIdx.y * BN + col0 + ni * 16 + lr;
        if constexpr (EPI == EPI_GELU_BF16) {
          p.Ob[(long)m * p.N + n] = __float2bfloat16(gelu_f(v + p.bias[n]));
        } else if constexpr (EPI == EPI_CONV2) {
          float t = gelu_f(v + p.bias[n]) + p.aux[(long)(m & 1023) * 768 + n];
          p.Of[(long)m * 768 + n] = t;
          p.Ob[(long)m * 768 + n] = __float2bfloat16(t);
        } else if constexpr (EPI == EPI_QKV) {
          float t = v + p.bias[n];
          int which = n / 768, nn = n - which * 768;
          int h = nn >> 6, d = nn & 63;
          long bh = (long)(m >> 10) * 12 + h;
          if (which < 2)
            p.Ob[(long)which * 3145728 + (bh << 16) + ((long)(m & 1023) << 6) + d] = __float2bfloat16(t);
          else
            p.Ob[6291456L + (bh << 16) + ((long)d << 10) + (m & 1023)] = __float2bfloat16(t);
        } else if constexpr (EPI == EPI_SBF) {
          p.Ob[(long)z * p.sC + (long)m * p.N + n] = __float2bfloat16(v);
        } else if constexpr (EPI == EPI_CC) {
          int bh = z + p.zoff; int b = bh / 12, h = bh - b * 12;
          p.Ob[((long)(b << 10) + m) * 768 + (h << 6) + n] = __float2bfloat16(v);
        } else if constexpr (EPI == EPI_BIAS_F32) {
          p.Of[(long)m * p.N + n] = v + p.bias[n];
        } else if constexpr (EPI == EPI_RELU_BF16) {
          p.Ob[(long)m * p.N + n] = __float2bfloat16(fmaxf(v + p.bias[n], 0.f));
        }
      }
    }
  }
}

// ---------------- softmax (in-place, rows of 1024 bf16) ----------------
__global__ __launch_bounds__(256)
void softmax_inplace(bf16* __restrict__ s) {
  __shared__ float red[4];
  long row = blockIdx.x;
  bf16* pr = s + (row << 10);
  int tid = threadIdx.x;
  float v[4];
#pragma unroll
  for (int i = 0; i < 4; ++i) v[i] = __bfloat162float(pr[tid + (i << 8)]);
  float mx = fmaxf(fmaxf(v[0], v[1]), fmaxf(v[2], v[3]));
  mx = block_max(mx, red, tid);
  float e[4], sm = 0.f;
#pragma unroll
  for (int i = 0; i < 4; ++i) { e[i] = __expf(v[i] - mx); sm += e[i]; }
  sm = block_sum(sm, red, tid);
  float inv = 1.f / sm;
#pragma unroll
  for (int i = 0; i < 4; ++i) pr[tid + (i << 8)] = __float2bfloat16(e[i] * inv);
}

// ---------------- residual + LayerNorm (row=768) ----------------
__global__ __launch_bounds__(256)
void ln_resid(const float* __restrict__ xin, const float* __restrict__ add,
              const float* __restrict__ g, const float* __restrict__ bb,
              float* __restrict__ xo, bf16* __restrict__ xbo) {
  __shared__ float red[4];
  long row = blockIdx.x;
  const float* xr = xin + row * 768;
  const float* ar = add + row * 768;
  int tid = threadIdx.x;
  float v0 = xr[tid] + ar[tid];
  float v1 = xr[tid + 256] + ar[tid + 256];
  float v2 = xr[tid + 512] + ar[tid + 512];
  float mean = block_sum(v0 + v1 + v2, red, tid) * (1.f / 768.f);
  v0 -= mean; v1 -= mean; v2 -= mean;
  float var = block_sum(v0 * v0 + v1 * v1 + v2 * v2, red, tid) * (1.f / 768.f);
  float rs = rsqrtf(var + 1e-5f);
  float o0 = v0 * rs * g[tid]       + bb[tid];
  float o1 = v1 * rs * g[tid + 256] + bb[tid + 256];
  float o2 = v2 * rs * g[tid + 512] + bb[tid + 512];
  float* xro = xo + row * 768;
  bf16*  xbr = xbo + row * 768;
  xro[tid] = o0; xro[tid + 256] = o1; xro[tid + 512] = o2;
  xbr[tid] = __float2bfloat16(o0);
  xbr[tid + 256] = __float2bfloat16(o1);
  xbr[tid + 512] = __float2bfloat16(o2);
}

// ---------------- classifier head ----------------
__global__ __launch_bounds__(256)
void head_cls(const float* __restrict__ x,
              const float* __restrict__ lnpg, const float* __restrict__ lnpb,
              const float* __restrict__ hlng, const float* __restrict__ hlnb,
              float* __restrict__ cls) {
  __shared__ float red[4];
  int b = blockIdx.x, tid = threadIdx.x;
  const float* xr = x + (long)b * 1024 * 768;  // row t=0
  float v0 = xr[tid], v1 = xr[tid + 256], v2 = xr[tid + 512];
  float s = block_sum(v0 + v1 + v2, red, tid) * (1.f / 768.f);
  v0 -= s; v1 -= s; v2 -= s;
  float q = block_sum(v0 * v0 + v1 * v1 + v2 * v2, red, tid) * (1.f / 768.f);
  float r = rsqrtf(q + 1e-5f);
  v0 = v0 * r * lnpg[tid]       + lnpb[tid];
  v1 = v1 * r * lnpg[tid + 256] + lnpb[tid + 256];
  v2 = v2 * r * lnpg[tid + 512] + lnpb[tid + 512];
  s = block_sum(v0 + v1 + v2, red, tid) * (1.f / 768.f);
  v0 -= s; v1 -= s; v2 -= s;
  q = block_sum(v0 * v0 + v1 * v1 + v2 * v2, red, tid) * (1.f / 768.f);
  r = rsqrtf(q + 1e-5f);
  cls[b * 768 + tid]       = v0 * r * hlng[tid]       + hlnb[tid];
  cls[b * 768 + tid + 256] = v1 * r * hlng[tid + 256] + hlnb[tid + 256];
  cls[b * 768 + tid + 512] = v2 * r * hlng[tid + 512] + hlnb[tid + 512];
}

// split-K GEMV stage A
__global__ __launch_bounds__(256)
void mlp_part(const float* __restrict__ in, const float* __restrict__ wmat,
              float* __restrict__ part, int IN, int OUTP, int ET) {
  __shared__ float cin[4][96];
  __shared__ float red[8][32][16];
  int tid = threadIdx.x;
  int tx = tid & 31, ty = tid >> 5;
  int e0 = blockIdx.y * ET;
  for (int i = tid; i < 4 * ET; i += 256) {
    int b = i / ET, el = i - b * ET;
    cin[b][el] = in[b * IN + e0 + el];
  }
  __syncthreads();
  f32x4 acc[4] = {};
  const float* wp = wmat + (long)e0 * OUTP + (blockIdx.x * 32 + tx) * 4;
  const int iters = ET >> 3;
  for (int i = 0; i < iters; ++i) {
    int el = ty + i * 8;
    f32x4 w = *(const f32x4*)(wp + (long)el * OUTP);
#pragma unroll
    for (int b = 0; b < 4; ++b) acc[b] += cin[b][el] * w;
  }
#pragma unroll
  for (int b = 0; b < 4; ++b) *(f32x4*)&red[ty][tx][b * 4] = acc[b];
  __syncthreads();
  if (tid < 128) {
    int rx = tid & 31, b = tid >> 5;
    f32x4 s = {};
#pragma unroll
    for (int t = 0; t < 8; ++t) s += *(const f32x4*)&red[t][rx][b * 4];
    *(f32x4*)&part[((long)blockIdx.y * 4 + b) * OUTP + (blockIdx.x * 32 + rx) * 4] = s;
  }
}

__global__ __launch_bounds__(256)
void mlp_reduce(const float* __restrict__ part, const float* __restrict__ bias,
                float* __restrict__ out, int OUTP, int S, int relu) {
  int idx = blockIdx.x * 256 + threadIdx.x;
  int b = idx / OUTP, j = idx - b * OUTP;
  float s = bias[j];
  for (int t = 0; t < S; ++t) s += part[((long)t * 4 + b) * OUTP + j];
  out[idx] = relu ? fmaxf(s, 0.f) : s;
}

// C=527 logits in [4][640] padded rows
__global__ __launch_bounds__(256)
void head_softmax(const float* __restrict__ lg, float* __restrict__ out) {
  __shared__ float red[4];
  int b = blockIdx.x, tid = threadIdx.x;
  const float* r = lg + (long)b * 640;
  float v0 = r[tid];
  float v1 = tid + 256 < 527 ? r[tid + 256] : -1e30f;
  float v2 = tid + 512 < 527 ? r[tid + 512] : -1e30f;
  float mx = block_max(fmaxf(v0, fmaxf(v1, v2)), red, tid);
  float e0 = __expf(v0 - mx);
  float e1 = tid + 256 < 527 ? __expf(v1 - mx) : 0.f;
  float e2 = tid + 512 < 527 ? __expf(v2 - mx) : 0.f;
  float sm = block_sum(e0 + e1 + e2, red, tid);
  float inv = 1.f / sm;
  out[(long)b * 527 + tid] = e0 * inv;
  if (tid + 256 < 527) out[(long)b * 527 + tid + 256] = e1 * inv;
  if (tid + 512 < 527) out[(long)b * 527 + tid + 512] = e2 * inv;
}

// ---------------- launcher ----------------
extern "C" void kernel_launch(void* const* d_in, const int* in_sizes, int n_in,
                              void* d_out, int out_size, void* d_ws, size_t ws_size,
                              hipStream_t stream) {
  const float* x_in    = (const float*)d_in[0];
  const float* conv1_w = (const float*)d_in[1];
  const float* conv1_b = (const float*)d_in[2];
  const float* conv2_w = (const float*)d_in[3];
  const float* conv2_b = (const float*)d_in[4];
  const float* pos_emb = (const float*)d_in[5];
  const float* ln1_g   = (const float*)d_in[6];
  const float* ln1_b   = (const float*)d_in[7];
  const float* wq      = (const float*)d_in[8];
  const float* bq      = (const float*)d_in[9];
  const float* wk      = (const float*)d_in[10];
  const float* bk      = (const float*)d_in[11];
  const float* wv      = (const float*)d_in[12];
  const float* bv      = (const float*)d_in[13];
  const float* wo      = (const float*)d_in[14];
  const float* bo      = (const float*)d_in[15];
  const float* w1      = (const float*)d_in[16];
  const float* b1      = (const float*)d_in[17];
  const float* w2      = (const float*)d_in[18];
  const float* b2      = (const float*)d_in[19];
  const float* ln2_g   = (const float*)d_in[20];
  const float* ln2_b   = (const float*)d_in[21];
  const float* lnp_g   = (const float*)d_in[22];
  const float* lnp_b   = (const float*)d_in[23];
  const float* hln_g   = (const float*)d_in[24];
  const float* hln_b   = (const float*)d_in[25];
  const float* hw1     = (const float*)d_in[26];
  const float* hb1     = (const float*)d_in[27];
  const float* hw2     = (const float*)d_in[28];
  const float* hb2     = (const float*)d_in[29];

  // workspace layout
  char* w = (char*)d_ws;
  bf16*  wqkvT = (bf16*)(w);                      // 6*2304*768 bf16
  bf16*  woT   = (bf16*)(w + 21233664);           // 6*768*768
  bf16*  w1T   = (bf16*)(w + 28311552);           // 6*3072*768
  bf16*  w2T   = (bf16*)(w + 56623104);           // 6*768*3072
  bf16*  wc1T  = (bf16*)(w + 84934656);           // 768*256
  bf16*  wc2T  = (bf16*)(w + 85327872);           // 768*2304
  float* bqkv  = (float*)(w + 88866816);          // 6*2304 f32
  float* Xf    = (float*)(w + 88922112);          // 4096*768 f32
  bf16*  Xb    = (bf16*)(w + 101505024);          // 4096*768
  bf16*  qkv   = (bf16*)(w + 107796480);          // 3*4096*768
  bf16*  CC    = (bf16*)(w + 126670848);          // 4096*768
  float* ATTN  = (float*)(w + 132962304);         // 4096*768 f32
  char*  BIG   = w + 145545216;                   // 50,331,648 shared region
  bf16*  A1  = (bf16*)(BIG);                      // 8192*256   (conv phase)
  bf16*  Y1G = (bf16*)(BIG + 4194304);            // 8192*768   (conv phase)
  bf16*  A2  = (bf16*)(BIG + 16777216);           // 4096*2304  (conv phase)
  bf16*  SC  = (bf16*)(BIG);                      // 24*1024*1024 scores/P (attn)
  bf16*  Hh  = (bf16*)(BIG);                      // 4096*3072  (ffn phase)
  float* FFN = (float*)(BIG + 25165824);          // 4096*768 f32 (ffn phase)
  // head phase (aliases, used only after last FFN)
  float* CLS  = (float*)(BIG);                    // 4*768
  float* HID  = (float*)(BIG + 16384);            // 4*3072
  float* LGT  = (float*)(BIG + 81920);            // 4*640
  float* PT1  = (float*)(BIG + 131072);           // 16*4*3072
  float* PT2  = (float*)(BIG + 1048576);          // 32*4*640
  float* HB2P = (float*)(BIG + 1572864);          // 640
  float* HW2P = (float*)(BIG + 1605632);          // 3072*640

  // ---- weight prep ----
  tconv<<<dim3(2, 24, 72), 256, 0, stream>>>(wq, wqkvT,            768, 64,   49152L, 1769472L, 49152L, 12);
  tconv<<<dim3(2, 24, 72), 256, 0, stream>>>(wk, wqkvT + 589824,   768, 64,   49152L, 1769472L, 49152L, 12);
  tconv<<<dim3(2, 24, 72), 256, 0, stream>>>(wv, wqkvT + 1179648,  768, 64,   49152L, 1769472L, 49152L, 12);
  tconv<<<dim3(24, 24, 6), 256, 0, stream>>>(wo, woT,              768, 768,  589824L, 589824L, 0L, 1);
  tconv<<<dim3(96, 24, 6), 256, 0, stream>>>(w1, w1T,              768, 3072, 2359296L, 2359296L, 0L, 1);
  tconv<<<dim3(24, 96, 6), 256, 0, stream>>>(w2, w2T,              3072, 768, 2359296L, 2359296L, 0L, 1);
  prep_cw<<<768,  256, 0, stream>>>(conv1_w, wc1T, 80, 256);
  prep_cw<<<6912, 256, 0, stream>>>(conv2_w, wc2T, 768, 2304);
  prep_bias<<<54, 256, 0, stream>>>(bq, bk, bv, bqkv);

  // ---- convs ----
  im2col1<<<8192, 256, 0, stream>>>(x_in, A1);
  { GP p{}; p.A = A1; p.B = wc1T; p.bias = conv1_b; p.Ob = Y1G;
    p.M = 8192; p.N = 768; p.K = 256;
    gemm_bt<128,64,2,2,EPI_GELU_BF16><<<dim3(64,12,1),256,0,stream>>>(p); }
  im2col2<<<36864, 256, 0, stream>>>(Y1G, A2);
  { GP p{}; p.A = A2; p.B = wc2T; p.bias = conv2_b; p.Of = Xf; p.Ob = Xb; p.aux = pos_emb;
    p.M = 4096; p.N = 768; p.K = 2304;
    gemm_bt<128,64,2,2,EPI_CONV2><<<dim3(32,12,1),256,0,stream>>>(p); }

  // ---- transformer layers ----
  for (int l = 0; l < 6; ++l) {
    { GP p{}; p.A = Xb; p.B = wqkvT + (long)l * 1769472; p.bias = bqkv + l * 2304;
      p.Ob = qkv; p.M = 4096; p.N = 2304; p.K = 768;
      gemm_bt<128,128,2,2,EPI_QKV><<<dim3(32,18,1),256,0,stream>>>(p); }
    for (int ch = 0; ch < 2; ++ch) {
      long co = (long)ch * 24 * 65536;
      { GP p{}; p.A = qkv + co; p.B = qkv + 3145728 + co; p.Ob = SC;
        p.M = 1024; p.N = 1024; p.K = 64; p.sA = 65536; p.sB = 65536; p.sC = 1048576;
        gemm_bt<128,128,2,2,EPI_SBF><<<dim3(8,8,24),256,0,stream>>>(p); }
      softmax_inplace<<<24576, 256, 0, stream>>>(SC);
      { GP p{}; p.A = SC; p.B = qkv + 6291456 + co; p.Ob = CC;
        p.M = 1024; p.N = 64; p.K = 1024; p.sA = 1048576; p.sB = 65536; p.zoff = ch * 24;
        gemm_bt<64,64,2,2,EPI_CC><<<dim3(16,1,24),256,0,stream>>>(p); }
    }
    { GP p{}; p.A = CC; p.B = woT + (long)l * 589824; p.bias = bo + l * 768; p.Of = ATTN;
      p.M = 4096; p.N = 768; p.K = 768;
      gemm_bt<128,64,2,2,EPI_BIAS_F32><<<dim3(32,12,1),256,0,stream>>>(p); }
    ln_resid<<<4096, 256, 0, stream>>>(Xf, ATTN, ln1_g + l * 768, ln1_b + l * 768, Xf, Xb);
    { GP p{}; p.A = Xb; p.B = w1T + (long)l * 2359296; p.bias = b1 + l * 3072; p.Ob = Hh;
      p.M = 4096; p.N = 3072; p.K = 768;
      gemm_bt<128,128,2,2,EPI_RELU_BF16><<<dim3(32,24,1),256,0,stream>>>(p); }
    { GP p{}; p.A = Hh; p.B = w2T + (long)l * 2359296; p.bias = b2 + l * 768; p.Of = FFN;
      p.M = 4096; p.N = 768; p.K = 3072;
      gemm_bt<128,64,2,2,EPI_BIAS_F32><<<dim3(32,12,1),256,0,stream>>>(p); }
    ln_resid<<<4096, 256, 0, stream>>>(Xf, FFN, ln2_g + l * 768, ln2_b + l * 768, Xf, Xb);
  }

  // ---- head ----
  head_cls<<<4, 256, 0, stream>>>(Xf, lnp_g, lnp_b, hln_g, hln_b, CLS);
  prep_hw2<<<7680, 256, 0, stream>>>(hw2, hb2, HW2P, HB2P);
  mlp_part<<<dim3(24, 16), 256, 0, stream>>>(CLS, hw1, PT1, 768, 3072, 48);
  mlp_reduce<<<48, 256, 0, stream>>>(PT1, hb1, HID, 3072, 16, 1);
  mlp_part<<<dim3(5, 32), 256, 0, stream>>>(HID, HW2P, PT2, 3072, 640, 96);
  mlp_reduce<<<10, 256, 0, stream>>>(PT2, HB2P, LGT, 640, 32, 0);
  head_softmax<<<4, 256, 0, stream>>>(LGT, (float*)d_out);
}

// Round 6
// 1923.900 us; speedup vs baseline: 1.1049x; 1.1049x over previous
//
#include <hip/hip_runtime.h>
#include <hip/hip_bf16.h>

typedef __hip_bfloat16 bf16;
using v8s   = __attribute__((ext_vector_type(8))) short;
using f32x4 = __attribute__((ext_vector_type(4))) float;

#define DI __device__ __forceinline__

DI float gelu_f(float x) { return 0.5f * x * (1.f + erff(x * 0.70710678118654752f)); }

DI void g2lds16(const bf16* g, bf16* l) {
  __builtin_amdgcn_global_load_lds((const __attribute__((address_space(1))) void*)g,
                                   (__attribute__((address_space(3))) void*)l, 16, 0, 0);
}

// ---------------- block reduction helpers (256 threads, 4 waves) ----------------
DI float block_sum(float v, float* red, int tid) {
#pragma unroll
  for (int o = 32; o > 0; o >>= 1) v += __shfl_down(v, o);
  __syncthreads();
  if ((tid & 63) == 0) red[tid >> 6] = v;
  __syncthreads();
  return red[0] + red[1] + red[2] + red[3];
}
DI float block_max(float v, float* red, int tid) {
#pragma unroll
  for (int o = 32; o > 0; o >>= 1) v = fmaxf(v, __shfl_down(v, o));
  __syncthreads();
  if ((tid & 63) == 0) red[tid >> 6] = v;
  __syncthreads();
  return fmaxf(fmaxf(red[0], red[1]), fmaxf(red[2], red[3]));
}

// ---------------- weight prep ----------------
__global__ __launch_bounds__(256)
void tconv(const float* __restrict__ in, bf16* __restrict__ out,
           int R, int C, long inStrideZ, long outStrideL, long outStrideH, int zmod) {
  __shared__ float tile[32][33];
  int z = blockIdx.z;
  int lz = z / zmod, hz = z - lz * zmod;
  in  += (long)z * inStrideZ;
  out += (long)lz * outStrideL + (long)hz * outStrideH;
  int cb = blockIdx.x * 32, rb = blockIdx.y * 32;
  int tx = threadIdx.x & 31, ty = threadIdx.x >> 5;  // 32x8
#pragma unroll
  for (int i = 0; i < 32; i += 8)
    tile[ty + i][tx] = in[(long)(rb + ty + i) * C + cb + tx];
  __syncthreads();
#pragma unroll
  for (int i = 0; i < 32; i += 8)
    out[(long)(cb + ty + i) * R + rb + tx] = __float2bfloat16(tile[tx][ty + i]);
}

__global__ __launch_bounds__(256)
void prep_cw(const float* __restrict__ wsrc, bf16* __restrict__ o, int IC, int KT) {
  int idx = blockIdx.x * 256 + threadIdx.x;
  int oc = idx / KT, kp = idx - oc * KT;
  float v = 0.f;
  if (kp < IC * 3) {
    int kk = kp / IC, ic = kp - kk * IC;
    v = wsrc[(oc * IC + ic) * 3 + kk];
  }
  o[idx] = __float2bfloat16(v);
}

__global__ __launch_bounds__(256)
void prep_bias(const float* __restrict__ bq, const float* __restrict__ bk,
               const float* __restrict__ bv, float* __restrict__ o) {
  int idx = blockIdx.x * 256 + threadIdx.x;  // 6*2304
  int l = idx / 2304, n = idx - l * 2304;
  int which = n / 768, r = n - which * 768;
  const float* src = which == 0 ? bq : (which == 1 ? bk : bv);
  o[idx] = src[l * 768 + r];
}

// pad-repack head layer-2 weights: hw2 [3072][527] -> hw2p [3072][640] (zero pad)
__global__ __launch_bounds__(256)
void prep_hw2(const float* __restrict__ hw2, const float* __restrict__ hb2,
              float* __restrict__ hw2p, float* __restrict__ hb2p) {
  int idx = blockIdx.x * 256 + threadIdx.x;  // 3072*640
  int e = idx / 640, c = idx - e * 640;
  hw2p[idx] = c < 527 ? hw2[(long)e * 527 + c] : 0.f;
  if (idx < 640) hb2p[idx] = idx < 527 ? hb2[idx] : 0.f;
}

// ---------------- im2col ----------------
__global__ __launch_bounds__(256)
void im2col1(const float* __restrict__ x, bf16* __restrict__ out) {
  int idx = blockIdx.x * 256 + threadIdx.x;  // 8192*256
  int m = idx >> 8, kp = idx & 255;
  float v = 0.f;
  if (kp < 240) {
    int kk = kp / 80, ic = kp - kk * 80;
    int t = (m & 2047) + kk - 1;
    int b = m >> 11;
    if ((unsigned)t < 2048u) v = x[((long)(b * 80 + ic) << 11) + t];
  }
  out[idx] = __float2bfloat16(v);
}

__global__ __launch_bounds__(256)
void im2col2(const bf16* __restrict__ y, bf16* __restrict__ out) {
  int idx = blockIdx.x * 256 + threadIdx.x;  // 4096*2304
  int m = idx / 2304, kp = idx - m * 2304;
  int kk = kp / 768, ic = kp - kk * 768;
  int t = 2 * (m & 1023) + kk - 1;
  bf16 v = __float2bfloat16(0.f);
  if ((unsigned)t < 2048u) v = y[((long)(m >> 10) * 2048 + t) * 768 + ic];
  out[idx] = v;
}

// ---------------- GEMM: C[m][n] = sum_k A[m][k]*B[n][k]  (both bf16, K%64==0) ----------------
enum { EPI_GELU_BF16, EPI_CONV2, EPI_QKV, EPI_BIAS_F32, EPI_RELU_BF16 };

struct GP {
  const bf16* A; const bf16* B; const float* bias;
  bf16* Ob; float* Of; const float* aux;
  int M, N, K; long sA, sB, sC; int zoff;
};

template<int BM, int BN, int WM, int WN, int EPI>
__global__ __launch_bounds__(256)
void gemm_bt(GP p) {
  constexpr int FM = BM / WM / 16, FN = BN / WN / 16;
  __shared__ __align__(16) bf16 As0[BM * 64], Bs0[BN * 64];
  __shared__ __align__(16) bf16 As1[BM * 64], Bs1[BN * 64];
  const int tid = threadIdx.x;
  const int lane = tid & 63, wid = tid >> 6;
  const int wr = wid / WN, wc = wid - wr * WN;
  const int row0 = wr * (BM / WM), col0 = wc * (BN / WN);
  const int lr = lane & 15, lk = (lane >> 4) * 8;
  const int lrow = lane >> 3, lcol = (lane & 7) * 8;
  const int z = blockIdx.z;
  const bf16* Ab = p.A + (long)z * p.sA + (long)blockIdx.x * BM * p.K;
  const bf16* Bb = p.B + (long)z * p.sB + (long)blockIdx.y * BN * p.K;
  f32x4 acc[FM][FN] = {};

  auto stage = [&](bf16* As, bf16* Bs, int kt) {
#pragma unroll
    for (int i = 0; i < BM / 32; ++i) {
      const int c = wid + i * 4;
      g2lds16(&Ab[(long)(c * 8 + lrow) * p.K + kt + lcol], &As[c << 9]);
    }
#pragma unroll
    for (int i = 0; i < BN / 32; ++i) {
      const int c = wid + i * 4;
      g2lds16(&Bb[(long)(c * 8 + lrow) * p.K + kt + lcol], &Bs[c << 9]);
    }
  };

  auto compute = [&](const bf16* As, const bf16* Bs) {
#pragma unroll
    for (int ks = 0; ks < 2; ++ks) {
      v8s af[FM], bf_[FN];
#pragma unroll
      for (int mi = 0; mi < FM; ++mi)
        af[mi] = *(const v8s*)&As[(row0 + mi * 16 + lr) * 64 + ks * 32 + lk];
#pragma unroll
      for (int ni = 0; ni < FN; ++ni)
        bf_[ni] = *(const v8s*)&Bs[(col0 + ni * 16 + lr) * 64 + ks * 32 + lk];
#pragma unroll
      for (int mi = 0; mi < FM; ++mi)
#pragma unroll
        for (int ni = 0; ni < FN; ++ni)
          acc[mi][ni] = __builtin_amdgcn_mfma_f32_16x16x32_bf16(af[mi], bf_[ni], acc[mi][ni], 0, 0, 0);
    }
  };

  stage(As0, Bs0, 0);
  __syncthreads();
  int kt = 0;
  while (true) {
    if (kt + 64 < p.K) stage(As1, Bs1, kt + 64);
    compute(As0, Bs0);
    __syncthreads();
    kt += 64;
    if (kt >= p.K) break;
    if (kt + 64 < p.K) stage(As0, Bs0, kt + 64);
    compute(As1, Bs1);
    __syncthreads();
    kt += 64;
    if (kt >= p.K) break;
  }

  // epilogue; D: row=(lane>>4)*4+r, col=lane&15
#pragma unroll
  for (int mi = 0; mi < FM; ++mi) {
#pragma unroll
    for (int ni = 0; ni < FN; ++ni) {
#pragma unroll
      for (int r = 0; r < 4; ++r) {
        float v = acc[mi][ni][r];
        const int m = blockIdx.x * BM + row0 + mi * 16 + (lane >> 4) * 4 + r;
        const int n = blockIdx.y * BN + col0 + ni * 16 + lr;
        if constexpr (EPI == EPI_GELU_BF16) {
          p.Ob[(long)m * p.N + n] = __float2bfloat16(gelu_f(v + p.bias[n]));
        } else if constexpr (EPI == EPI_CONV2) {
          float t = gelu_f(v + p.bias[n]) + p.aux[(long)(m & 1023) * 768 + n];
          p.Of[(long)m * 768 + n] = t;
          p.Ob[(long)m * 768 + n] = __float2bfloat16(t);
        } else if constexpr (EPI == EPI_QKV) {
          float t = v + p.bias[n];
          int which = n / 768, nn = n - which * 768;
          int h = nn >> 6, d = nn & 63;
          long bh = (long)(m >> 10) * 12 + h;
          if (which < 2)
            p.Ob[(long)which * 3145728 + (bh << 16) + ((long)(m & 1023) << 6) + d] = __float2bfloat16(t);
          else
            p.Ob[6291456L + (bh << 16) + ((long)d << 10) + (m & 1023)] = __float2bfloat16(t);
        } else if constexpr (EPI == EPI_BIAS_F32) {
          p.Of[(long)m * p.N + n] = v + p.bias[n];
        } else if constexpr (EPI == EPI_RELU_BF16) {
          p.Ob[(long)m * p.N + n] = __float2bfloat16(fmaxf(v + p.bias[n], 0.f));
        }
      }
    }
  }
}

// ---------------- fused flash attention ----------------
// grid (8 q-tiles, 48 bh), 256 threads = 4 waves x 32 q-rows.
// Q t-major [bh][t][64], K t-major [bh][t][64], V d-major [bh][d][1024].
// Per kv-tile (64): S = Q K^T (16 MFMA), online softmax, O += P V (16 MFMA).
// P transposed via per-wave padded LDS [32][76] (D-layout write, A-frag read).
__global__ __launch_bounds__(256)
void attn_flash(const bf16* __restrict__ qkv, bf16* __restrict__ cc) {
  __shared__ __align__(16) bf16 Ks[64 * 64], Vs[64 * 64];
  __shared__ __align__(16) bf16 Pl[4][32 * 76];
  const int tid = threadIdx.x, lane = tid & 63, wid = tid >> 6;
  const int lr = lane & 15, lg = lane >> 4;
  const int bh = blockIdx.y, b = bh / 12, h = bh - b * 12;
  const long qb = (long)bh << 16;
  const bf16* Qg = qkv + qb;
  const bf16* Kg = qkv + 3145728 + qb;
  const bf16* Vg = qkv + 6291456 + qb;
  const int q0 = blockIdx.x * 128 + wid * 32;
  const int lrow8 = lane >> 3, lcol8 = (lane & 7) * 8;

  v8s aq[2][2];
#pragma unroll
  for (int mi = 0; mi < 2; ++mi)
#pragma unroll
    for (int ks = 0; ks < 2; ++ks)
      aq[mi][ks] = *(const v8s*)&Qg[(long)(q0 + mi * 16 + lr) * 64 + ks * 32 + lg * 8];

  float mrow[2][4], lrow_[2][4];
  f32x4 acc[2][4] = {};
#pragma unroll
  for (int mi = 0; mi < 2; ++mi)
#pragma unroll
    for (int r = 0; r < 4; ++r) { mrow[mi][r] = -1e30f; lrow_[mi][r] = 0.f; }
  bf16* myP = &Pl[wid][0];

  for (int kt = 0; kt < 1024; kt += 64) {
    __syncthreads();  // previous iter's K/V reads done
#pragma unroll
    for (int i = 0; i < 2; ++i) {
      int c = wid + i * 4;
      g2lds16(&Kg[(long)(kt + c * 8 + lrow8) * 64 + lcol8], &Ks[c << 9]);
      g2lds16(&Vg[((long)(c * 8 + lrow8) << 10) + kt + lcol8], &Vs[c << 9]);
    }
    __syncthreads();  // staging complete (vmcnt drained at barrier)

    // S = Q K^T
    f32x4 s[2][4] = {};
#pragma unroll
    for (int ks = 0; ks < 2; ++ks) {
      v8s bk[4];
#pragma unroll
      for (int ni = 0; ni < 4; ++ni)
        bk[ni] = *(const v8s*)&Ks[(ni * 16 + lr) * 64 + ks * 32 + lg * 8];
#pragma unroll
      for (int mi = 0; mi < 2; ++mi)
#pragma unroll
        for (int ni = 0; ni < 4; ++ni)
          s[mi][ni] = __builtin_amdgcn_mfma_f32_16x16x32_bf16(aq[mi][ks], bk[ni], s[mi][ni], 0, 0, 0);
    }

    // online softmax; write P (bf16) to per-wave LDS
#pragma unroll
    for (int mi = 0; mi < 2; ++mi) {
#pragma unroll
      for (int r = 0; r < 4; ++r) {
        float tm = fmaxf(fmaxf(s[mi][0][r], s[mi][1][r]), fmaxf(s[mi][2][r], s[mi][3][r]));
#pragma unroll
        for (int o = 1; o < 16; o <<= 1) tm = fmaxf(tm, __shfl_xor(tm, o));
        float mn = fmaxf(mrow[mi][r], tm);
        float al = __expf(mrow[mi][r] - mn);
        mrow[mi][r] = mn;
        float ps = 0.f;
        const int prow = (mi * 16 + lg * 4 + r) * 76;
#pragma unroll
        for (int ni = 0; ni < 4; ++ni) {
          float pv = __expf(s[mi][ni][r] - mn);
          myP[prow + ni * 16 + lr] = __float2bfloat16(pv);
          ps += pv;
        }
#pragma unroll
        for (int o = 1; o < 16; o <<= 1) ps += __shfl_xor(ps, o);
        lrow_[mi][r] = lrow_[mi][r] * al + ps;
#pragma unroll
        for (int ni = 0; ni < 4; ++ni) acc[mi][ni][r] *= al;
      }
    }

    // O += P * V  (V^T rows are d-major -> contiguous B-frags)
#pragma unroll
    for (int ks = 0; ks < 2; ++ks) {
      v8s pa[2], bv[4];
#pragma unroll
      for (int mi = 0; mi < 2; ++mi)
        pa[mi] = *(const v8s*)&myP[(mi * 16 + lr) * 76 + ks * 32 + lg * 8];
#pragma unroll
      for (int ni = 0; ni < 4; ++ni)
        bv[ni] = *(const v8s*)&Vs[(ni * 16 + lr) * 64 + ks * 32 + lg * 8];
#pragma unroll
      for (int mi = 0; mi < 2; ++mi)
#pragma unroll
        for (int ni = 0; ni < 4; ++ni)
          acc[mi][ni] = __builtin_amdgcn_mfma_f32_16x16x32_bf16(pa[mi], bv[ni], acc[mi][ni], 0, 0, 0);
    }
  }

  // epilogue: normalize and write concat layout [b*1024+t][h*64+d]
#pragma unroll
  for (int mi = 0; mi < 2; ++mi)
#pragma unroll
    for (int ni = 0; ni < 4; ++ni)
#pragma unroll
      for (int r = 0; r < 4; ++r) {
        int row = q0 + mi * 16 + lg * 4 + r;
        cc[((long)(b << 10) + row) * 768 + h * 64 + ni * 16 + lr] =
            __float2bfloat16(acc[mi][ni][r] / lrow_[mi][r]);
      }
}

// ---------------- residual + LayerNorm (row=768) ----------------
__global__ __launch_bounds__(256)
void ln_resid(const float* __restrict__ xin, const float* __restrict__ add,
              const float* __restrict__ g, const float* __restrict__ bb,
              float* __restrict__ xo, bf16* __restrict__ xbo) {
  __shared__ float red[4];
  long row = blockIdx.x;
  const float* xr = xin + row * 768;
  const float* ar = add + row * 768;
  int tid = threadIdx.x;
  float v0 = xr[tid] + ar[tid];
  float v1 = xr[tid + 256] + ar[tid + 256];
  float v2 = xr[tid + 512] + ar[tid + 512];
  float mean = block_sum(v0 + v1 + v2, red, tid) * (1.f / 768.f);
  v0 -= mean; v1 -= mean; v2 -= mean;
  float var = block_sum(v0 * v0 + v1 * v1 + v2 * v2, red, tid) * (1.f / 768.f);
  float rs = rsqrtf(var + 1e-5f);
  float o0 = v0 * rs * g[tid]       + bb[tid];
  float o1 = v1 * rs * g[tid + 256] + bb[tid + 256];
  float o2 = v2 * rs * g[tid + 512] + bb[tid + 512];
  float* xro = xo + row * 768;
  bf16*  xbr = xbo + row * 768;
  xro[tid] = o0; xro[tid + 256] = o1; xro[tid + 512] = o2;
  xbr[tid] = __float2bfloat16(o0);
  xbr[tid + 256] = __float2bfloat16(o1);
  xbr[tid + 512] = __float2bfloat16(o2);
}

// ---------------- classifier head ----------------
__global__ __launch_bounds__(256)
void head_cls(const float* __restrict__ x,
              const float* __restrict__ lnpg, const float* __restrict__ lnpb,
              const float* __restrict__ hlng, const float* __restrict__ hlnb,
              float* __restrict__ cls) {
  __shared__ float red[4];
  int b = blockIdx.x, tid = threadIdx.x;
  const float* xr = x + (long)b * 1024 * 768;  // row t=0
  float v0 = xr[tid], v1 = xr[tid + 256], v2 = xr[tid + 512];
  float s = block_sum(v0 + v1 + v2, red, tid) * (1.f / 768.f);
  v0 -= s; v1 -= s; v2 -= s;
  float q = block_sum(v0 * v0 + v1 * v1 + v2 * v2, red, tid) * (1.f / 768.f);
  float r = rsqrtf(q + 1e-5f);
  v0 = v0 * r * lnpg[tid]       + lnpb[tid];
  v1 = v1 * r * lnpg[tid + 256] + lnpb[tid + 256];
  v2 = v2 * r * lnpg[tid + 512] + lnpb[tid + 512];
  s = block_sum(v0 + v1 + v2, red, tid) * (1.f / 768.f);
  v0 -= s; v1 -= s; v2 -= s;
  q = block_sum(v0 * v0 + v1 * v1 + v2 * v2, red, tid) * (1.f / 768.f);
  r = rsqrtf(q + 1e-5f);
  cls[b * 768 + tid]       = v0 * r * hlng[tid]       + hlnb[tid];
  cls[b * 768 + tid + 256] = v1 * r * hlng[tid + 256] + hlnb[tid + 256];
  cls[b * 768 + tid + 512] = v2 * r * hlng[tid + 512] + hlnb[tid + 512];
}

// split-K GEMV stage A
__global__ __launch_bounds__(256)
void mlp_part(const float* __restrict__ in, const float* __restrict__ wmat,
              float* __restrict__ part, int IN, int OUTP, int ET) {
  __shared__ float cin[4][96];
  __shared__ float red[8][32][16];
  int tid = threadIdx.x;
  int tx = tid & 31, ty = tid >> 5;
  int e0 = blockIdx.y * ET;
  for (int i = tid; i < 4 * ET; i += 256) {
    int b = i / ET, el = i - b * ET;
    cin[b][el] = in[b * IN + e0 + el];
  }
  __syncthreads();
  f32x4 acc[4] = {};
  const float* wp = wmat + (long)e0 * OUTP + (blockIdx.x * 32 + tx) * 4;
  const int iters = ET >> 3;
  for (int i = 0; i < iters; ++i) {
    int el = ty + i * 8;
    f32x4 w = *(const f32x4*)(wp + (long)el * OUTP);
#pragma unroll
    for (int b = 0; b < 4; ++b) acc[b] += cin[b][el] * w;
  }
#pragma unroll
  for (int b = 0; b < 4; ++b) *(f32x4*)&red[ty][tx][b * 4] = acc[b];
  __syncthreads();
  if (tid < 128) {
    int rx = tid & 31, b = tid >> 5;
    f32x4 s = {};
#pragma unroll
    for (int t = 0; t < 8; ++t) s += *(const f32x4*)&red[t][rx][b * 4];
    *(f32x4*)&part[((long)blockIdx.y * 4 + b) * OUTP + (blockIdx.x * 32 + rx) * 4] = s;
  }
}

__global__ __launch_bounds__(256)
void mlp_reduce(const float* __restrict__ part, const float* __restrict__ bias,
                float* __restrict__ out, int OUTP, int S, int relu) {
  int idx = blockIdx.x * 256 + threadIdx.x;
  int b = idx / OUTP, j = idx - b * OUTP;
  float s = bias[j];
  for (int t = 0; t < S; ++t) s += part[((long)t * 4 + b) * OUTP + j];
  out[idx] = relu ? fmaxf(s, 0.f) : s;
}

// C=527 logits in [4][640] padded rows
__global__ __launch_bounds__(256)
void head_softmax(const float* __restrict__ lg, float* __restrict__ out) {
  __shared__ float red[4];
  int b = blockIdx.x, tid = threadIdx.x;
  const float* r = lg + (long)b * 640;
  float v0 = r[tid];
  float v1 = tid + 256 < 527 ? r[tid + 256] : -1e30f;
  float v2 = tid + 512 < 527 ? r[tid + 512] : -1e30f;
  float mx = block_max(fmaxf(v0, fmaxf(v1, v2)), red, tid);
  float e0 = __expf(v0 - mx);
  float e1 = tid + 256 < 527 ? __expf(v1 - mx) : 0.f;
  float e2 = tid + 512 < 527 ? __expf(v2 - mx) : 0.f;
  float sm = block_sum(e0 + e1 + e2, red, tid);
  float inv = 1.f / sm;
  out[(long)b * 527 + tid] = e0 * inv;
  if (tid + 256 < 527) out[(long)b * 527 + tid + 256] = e1 * inv;
  if (tid + 512 < 527) out[(long)b * 527 + tid + 512] = e2 * inv;
}

// ---------------- launcher ----------------
extern "C" void kernel_launch(void* const* d_in, const int* in_sizes, int n_in,
                              void* d_out, int out_size, void* d_ws, size_t ws_size,
                              hipStream_t stream) {
  const float* x_in    = (const float*)d_in[0];
  const float* conv1_w = (const float*)d_in[1];
  const float* conv1_b = (const float*)d_in[2];
  const float* conv2_w = (const float*)d_in[3];
  const float* conv2_b = (const float*)d_in[4];
  const float* pos_emb = (const float*)d_in[5];
  const float* ln1_g   = (const float*)d_in[6];
  const float* ln1_b   = (const float*)d_in[7];
  const float* wq      = (const float*)d_in[8];
  const float* bq      = (const float*)d_in[9];
  const float* wk      = (const float*)d_in[10];
  const float* bk      = (const float*)d_in[11];
  const float* wv      = (const float*)d_in[12];
  const float* bv      = (const float*)d_in[13];
  const float* wo      = (const float*)d_in[14];
  const float* bo      = (const float*)d_in[15];
  const float* w1      = (const float*)d_in[16];
  const float* b1      = (const float*)d_in[17];
  const float* w2      = (const float*)d_in[18];
  const float* b2      = (const float*)d_in[19];
  const float* ln2_g   = (const float*)d_in[20];
  const float* ln2_b   = (const float*)d_in[21];
  const float* lnp_g   = (const float*)d_in[22];
  const float* lnp_b   = (const float*)d_in[23];
  const float* hln_g   = (const float*)d_in[24];
  const float* hln_b   = (const float*)d_in[25];
  const float* hw1     = (const float*)d_in[26];
  const float* hb1     = (const float*)d_in[27];
  const float* hw2     = (const float*)d_in[28];
  const float* hb2     = (const float*)d_in[29];

  // workspace layout
  char* w = (char*)d_ws;
  bf16*  wqkvT = (bf16*)(w);                      // 6*2304*768 bf16
  bf16*  woT   = (bf16*)(w + 21233664);           // 6*768*768
  bf16*  w1T   = (bf16*)(w + 28311552);           // 6*3072*768
  bf16*  w2T   = (bf16*)(w + 56623104);           // 6*768*3072
  bf16*  wc1T  = (bf16*)(w + 84934656);           // 768*256
  bf16*  wc2T  = (bf16*)(w + 85327872);           // 768*2304
  float* bqkv  = (float*)(w + 88866816);          // 6*2304 f32
  float* Xf    = (float*)(w + 88922112);          // 4096*768 f32
  bf16*  Xb    = (bf16*)(w + 101505024);          // 4096*768
  bf16*  qkv   = (bf16*)(w + 107796480);          // 3*4096*768 (q t-major, k t-major, v d-major)
  bf16*  CC    = (bf16*)(w + 126670848);          // 4096*768
  float* ATTN  = (float*)(w + 132962304);         // 4096*768 f32
  char*  BIG   = w + 145545216;                   // 50,331,648 shared region
  bf16*  A1  = (bf16*)(BIG);                      // 8192*256   (conv phase)
  bf16*  Y1G = (bf16*)(BIG + 4194304);            // 8192*768   (conv phase)
  bf16*  A2  = (bf16*)(BIG + 16777216);           // 4096*2304  (conv phase)
  bf16*  Hh  = (bf16*)(BIG);                      // 4096*3072  (ffn phase)
  float* FFN = (float*)(BIG + 25165824);          // 4096*768 f32 (ffn phase)
  // head phase (aliases, used only after last FFN)
  float* CLS  = (float*)(BIG);                    // 4*768
  float* HID  = (float*)(BIG + 16384);            // 4*3072
  float* LGT  = (float*)(BIG + 81920);            // 4*640
  float* PT1  = (float*)(BIG + 131072);           // 16*4*3072
  float* PT2  = (float*)(BIG + 1048576);          // 32*4*640
  float* HB2P = (float*)(BIG + 1572864);          // 640
  float* HW2P = (float*)(BIG + 1605632);          // 3072*640

  // ---- weight prep ----
  tconv<<<dim3(2, 24, 72), 256, 0, stream>>>(wq, wqkvT,            768, 64,   49152L, 1769472L, 49152L, 12);
  tconv<<<dim3(2, 24, 72), 256, 0, stream>>>(wk, wqkvT + 589824,   768, 64,   49152L, 1769472L, 49152L, 12);
  tconv<<<dim3(2, 24, 72), 256, 0, stream>>>(wv, wqkvT + 1179648,  768, 64,   49152L, 1769472L, 49152L, 12);
  tconv<<<dim3(24, 24, 6), 256, 0, stream>>>(wo, woT,              768, 768,  589824L, 589824L, 0L, 1);
  tconv<<<dim3(96, 24, 6), 256, 0, stream>>>(w1, w1T,              768, 3072, 2359296L, 2359296L, 0L, 1);
  tconv<<<dim3(24, 96, 6), 256, 0, stream>>>(w2, w2T,              3072, 768, 2359296L, 2359296L, 0L, 1);
  prep_cw<<<768,  256, 0, stream>>>(conv1_w, wc1T, 80, 256);
  prep_cw<<<6912, 256, 0, stream>>>(conv2_w, wc2T, 768, 2304);
  prep_bias<<<54, 256, 0, stream>>>(bq, bk, bv, bqkv);

  // ---- convs ----
  im2col1<<<8192, 256, 0, stream>>>(x_in, A1);
  { GP p{}; p.A = A1; p.B = wc1T; p.bias = conv1_b; p.Ob = Y1G;
    p.M = 8192; p.N = 768; p.K = 256;
    gemm_bt<128,64,2,2,EPI_GELU_BF16><<<dim3(64,12,1),256,0,stream>>>(p); }
  im2col2<<<36864, 256, 0, stream>>>(Y1G, A2);
  { GP p{}; p.A = A2; p.B = wc2T; p.bias = conv2_b; p.Of = Xf; p.Ob = Xb; p.aux = pos_emb;
    p.M = 4096; p.N = 768; p.K = 2304;
    gemm_bt<128,64,2,2,EPI_CONV2><<<dim3(32,12,1),256,0,stream>>>(p); }

  // ---- transformer layers ----
  for (int l = 0; l < 6; ++l) {
    { GP p{}; p.A = Xb; p.B = wqkvT + (long)l * 1769472; p.bias = bqkv + l * 2304;
      p.Ob = qkv; p.M = 4096; p.N = 2304; p.K = 768;
      gemm_bt<128,128,2,2,EPI_QKV><<<dim3(32,18,1),256,0,stream>>>(p); }
    attn_flash<<<dim3(8, 48), 256, 0, stream>>>(qkv, CC);
    { GP p{}; p.A = CC; p.B = woT + (long)l * 589824; p.bias = bo + l * 768; p.Of = ATTN;
      p.M = 4096; p.N = 768; p.K = 768;
      gemm_bt<128,64,2,2,EPI_BIAS_F32><<<dim3(32,12,1),256,0,stream>>>(p); }
    ln_resid<<<4096, 256, 0, stream>>>(Xf, ATTN, ln1_g + l * 768, ln1_b + l * 768, Xf, Xb);
    { GP p{}; p.A = Xb; p.B = w1T + (long)l * 2359296; p.bias = b1 + l * 3072; p.Ob = Hh;
      p.M = 4096; p.N = 3072; p.K = 768;
      gemm_bt<128,128,2,2,EPI_RELU_BF16><<<dim3(32,24,1),256,0,stream>>>(p); }
    { GP p{}; p.A = Hh; p.B = w2T + (long)l * 2359296; p.bias = b2 + l * 768; p.Of = FFN;
      p.M = 4096; p.N = 768; p.K = 3072;
      gemm_bt<128,64,2,2,EPI_BIAS_F32><<<dim3(32,12,1),256,0,stream>>>(p); }
    ln_resid<<<4096, 256, 0, stream>>>(Xf, FFN, ln2_g + l * 768, ln2_b + l * 768, Xf, Xb);
  }

  // ---- head ----
  head_cls<<<4, 256, 0, stream>>>(Xf, lnp_g, lnp_b, hln_g, hln_b, CLS);
  prep_hw2<<<7680, 256, 0, stream>>>(hw2, hb2, HW2P, HB2P);
  mlp_part<<<dim3(24, 16), 256, 0, stream>>>(CLS, hw1, PT1, 768, 3072, 48);
  mlp_reduce<<<48, 256, 0, stream>>>(PT1, hb1, HID, 3072, 16, 1);
  mlp_part<<<dim3(5, 32), 256, 0, stream>>>(HID, HW2P, PT2, 3072, 640, 96);
  mlp_reduce<<<10, 256, 0, stream>>>(PT2, HB2P, LGT, 640, 32, 0);
  head_softmax<<<4, 256, 0, stream>>>(LGT, (float*)d_out);
}

// Round 7
// 1918.835 us; speedup vs baseline: 1.1078x; 1.0026x over previous
//
#include <hip/hip_runtime.h>
#include <hip/hip_bf16.h>

typedef __hip_bfloat16 bf16;
using v8s   = __attribute__((ext_vector_type(8))) short;
using f32x4 = __attribute__((ext_vector_type(4))) float;

#define DI __device__ __forceinline__

DI float gelu_f(float x) { return 0.5f * x * (1.f + erff(x * 0.70710678118654752f)); }

DI void g2lds16(const bf16* g, bf16* l) {
  __builtin_amdgcn_global_load_lds((const __attribute__((address_space(1))) void*)g,
                                   (__attribute__((address_space(3))) void*)l, 16, 0, 0);
}

// ---------------- block reduction helpers (256 threads, 4 waves) ----------------
DI float block_sum(float v, float* red, int tid) {
#pragma unroll
  for (int o = 32; o > 0; o >>= 1) v += __shfl_down(v, o);
  __syncthreads();
  if ((tid & 63) == 0) red[tid >> 6] = v;
  __syncthreads();
  return red[0] + red[1] + red[2] + red[3];
}
DI float block_max(float v, float* red, int tid) {
#pragma unroll
  for (int o = 32; o > 0; o >>= 1) v = fmaxf(v, __shfl_down(v, o));
  __syncthreads();
  if ((tid & 63) == 0) red[tid >> 6] = v;
  __syncthreads();
  return fmaxf(fmaxf(red[0], red[1]), fmaxf(red[2], red[3]));
}

// ---------------- weight prep ----------------
__global__ __launch_bounds__(256)
void tconv(const float* __restrict__ in, bf16* __restrict__ out,
           int R, int C, long inStrideZ, long outStrideL, long outStrideH, int zmod) {
  __shared__ float tile[32][33];
  int z = blockIdx.z;
  int lz = z / zmod, hz = z - lz * zmod;
  in  += (long)z * inStrideZ;
  out += (long)lz * outStrideL + (long)hz * outStrideH;
  int cb = blockIdx.x * 32, rb = blockIdx.y * 32;
  int tx = threadIdx.x & 31, ty = threadIdx.x >> 5;  // 32x8
#pragma unroll
  for (int i = 0; i < 32; i += 8)
    tile[ty + i][tx] = in[(long)(rb + ty + i) * C + cb + tx];
  __syncthreads();
#pragma unroll
  for (int i = 0; i < 32; i += 8)
    out[(long)(cb + ty + i) * R + rb + tx] = __float2bfloat16(tile[tx][ty + i]);
}

__global__ __launch_bounds__(256)
void prep_cw(const float* __restrict__ wsrc, bf16* __restrict__ o, int IC, int KT) {
  int idx = blockIdx.x * 256 + threadIdx.x;
  int oc = idx / KT, kp = idx - oc * KT;
  float v = 0.f;
  if (kp < IC * 3) {
    int kk = kp / IC, ic = kp - kk * IC;
    v = wsrc[(oc * IC + ic) * 3 + kk];
  }
  o[idx] = __float2bfloat16(v);
}

__global__ __launch_bounds__(256)
void prep_bias(const float* __restrict__ bq, const float* __restrict__ bk,
               const float* __restrict__ bv, float* __restrict__ o) {
  int idx = blockIdx.x * 256 + threadIdx.x;  // 6*2304
  int l = idx / 2304, n = idx - l * 2304;
  int which = n / 768, r = n - which * 768;
  const float* src = which == 0 ? bq : (which == 1 ? bk : bv);
  o[idx] = src[l * 768 + r];
}

// pad-repack head layer-2 weights: hw2 [3072][527] -> hw2p [3072][640] (zero pad)
__global__ __launch_bounds__(256)
void prep_hw2(const float* __restrict__ hw2, const float* __restrict__ hb2,
              float* __restrict__ hw2p, float* __restrict__ hb2p) {
  int idx = blockIdx.x * 256 + threadIdx.x;  // 3072*640
  int e = idx / 640, c = idx - e * 640;
  hw2p[idx] = c < 527 ? hw2[(long)e * 527 + c] : 0.f;
  if (idx < 640) hb2p[idx] = idx < 527 ? hb2[idx] : 0.f;
}

// ---------------- im2col ----------------
__global__ __launch_bounds__(256)
void im2col1(const float* __restrict__ x, bf16* __restrict__ out) {
  int idx = blockIdx.x * 256 + threadIdx.x;  // 8192*256
  int m = idx >> 8, kp = idx & 255;
  float v = 0.f;
  if (kp < 240) {
    int kk = kp / 80, ic = kp - kk * 80;
    int t = (m & 2047) + kk - 1;
    int b = m >> 11;
    if ((unsigned)t < 2048u) v = x[((long)(b * 80 + ic) << 11) + t];
  }
  out[idx] = __float2bfloat16(v);
}

__global__ __launch_bounds__(256)
void im2col2(const bf16* __restrict__ y, bf16* __restrict__ out) {
  int idx = blockIdx.x * 256 + threadIdx.x;  // 4096*2304
  int m = idx / 2304, kp = idx - m * 2304;
  int kk = kp / 768, ic = kp - kk * 768;
  int t = 2 * (m & 1023) + kk - 1;
  bf16 v = __float2bfloat16(0.f);
  if ((unsigned)t < 2048u) v = y[((long)(m >> 10) * 2048 + t) * 768 + ic];
  out[idx] = v;
}

// ---------------- GEMM: C[m][n] = sum_k A[m][k]*B[n][k]  (both bf16, K%64==0) ----------------
enum { EPI_GELU_BF16, EPI_CONV2, EPI_QKV, EPI_BIAS_F32, EPI_RELU_BF16 };

struct GP {
  const bf16* A; const bf16* B; const float* bias;
  bf16* Ob; float* Of; const float* aux;
  int M, N, K; long sA, sB, sC; int zoff;
};

template<int BM, int BN, int WM, int WN, int EPI>
__global__ __launch_bounds__(256)
void gemm_bt(GP p) {
  constexpr int FM = BM / WM / 16, FN = BN / WN / 16;
  __shared__ __align__(16) bf16 As0[BM * 64], Bs0[BN * 64];
  __shared__ __align__(16) bf16 As1[BM * 64], Bs1[BN * 64];
  const int tid = threadIdx.x;
  const int lane = tid & 63, wid = tid >> 6;
  const int wr = wid / WN, wc = wid - wr * WN;
  const int row0 = wr * (BM / WM), col0 = wc * (BN / WN);
  const int lr = lane & 15, lk = (lane >> 4) * 8;
  const int lrow = lane >> 3, lcol = (lane & 7) * 8;
  const int z = blockIdx.z;
  const bf16* Ab = p.A + (long)z * p.sA + (long)blockIdx.x * BM * p.K;
  const bf16* Bb = p.B + (long)z * p.sB + (long)blockIdx.y * BN * p.K;
  f32x4 acc[FM][FN] = {};

  auto stage = [&](bf16* As, bf16* Bs, int kt) {
#pragma unroll
    for (int i = 0; i < BM / 32; ++i) {
      const int c = wid + i * 4;
      g2lds16(&Ab[(long)(c * 8 + lrow) * p.K + kt + lcol], &As[c << 9]);
    }
#pragma unroll
    for (int i = 0; i < BN / 32; ++i) {
      const int c = wid + i * 4;
      g2lds16(&Bb[(long)(c * 8 + lrow) * p.K + kt + lcol], &Bs[c << 9]);
    }
  };

  auto compute = [&](const bf16* As, const bf16* Bs) {
#pragma unroll
    for (int ks = 0; ks < 2; ++ks) {
      v8s af[FM], bf_[FN];
#pragma unroll
      for (int mi = 0; mi < FM; ++mi)
        af[mi] = *(const v8s*)&As[(row0 + mi * 16 + lr) * 64 + ks * 32 + lk];
#pragma unroll
      for (int ni = 0; ni < FN; ++ni)
        bf_[ni] = *(const v8s*)&Bs[(col0 + ni * 16 + lr) * 64 + ks * 32 + lk];
#pragma unroll
      for (int mi = 0; mi < FM; ++mi)
#pragma unroll
        for (int ni = 0; ni < FN; ++ni)
          acc[mi][ni] = __builtin_amdgcn_mfma_f32_16x16x32_bf16(af[mi], bf_[ni], acc[mi][ni], 0, 0, 0);
    }
  };

  stage(As0, Bs0, 0);
  __syncthreads();
  int kt = 0;
  while (true) {
    if (kt + 64 < p.K) stage(As1, Bs1, kt + 64);
    compute(As0, Bs0);
    __syncthreads();
    kt += 64;
    if (kt >= p.K) break;
    if (kt + 64 < p.K) stage(As0, Bs0, kt + 64);
    compute(As1, Bs1);
    __syncthreads();
    kt += 64;
    if (kt >= p.K) break;
  }

  // epilogue; D: row=(lane>>4)*4+r, col=lane&15
#pragma unroll
  for (int mi = 0; mi < FM; ++mi) {
#pragma unroll
    for (int ni = 0; ni < FN; ++ni) {
#pragma unroll
      for (int r = 0; r < 4; ++r) {
        float v = acc[mi][ni][r];
        const int m = blockIdx.x * BM + row0 + mi * 16 + (lane >> 4) * 4 + r;
        const int n = blockIdx.y * BN + col0 + ni * 16 + lr;
        if constexpr (EPI == EPI_GELU_BF16) {
          p.Ob[(long)m * p.N + n] = __float2bfloat16(gelu_f(v + p.bias[n]));
        } else if constexpr (EPI == EPI_CONV2) {
          float t = gelu_f(v + p.bias[n]) + p.aux[(long)(m & 1023) * 768 + n];
          p.Of[(long)m * 768 + n] = t;
          p.Ob[(long)m * 768 + n] = __float2bfloat16(t);
        } else if constexpr (EPI == EPI_QKV) {
          float t = v + p.bias[n];
          int which = n / 768, nn = n - which * 768;
          int h = nn >> 6, d = nn & 63;
          long bh = (long)(m >> 10) * 12 + h;
          if (which < 2)
            p.Ob[(long)which * 3145728 + (bh << 16) + ((long)(m & 1023) << 6) + d] = __float2bfloat16(t);
          else
            p.Ob[6291456L + (bh << 16) + ((long)d << 10) + (m & 1023)] = __float2bfloat16(t);
        } else if constexpr (EPI == EPI_BIAS_F32) {
          p.Of[(long)m * p.N + n] = v + p.bias[n];
        } else if constexpr (EPI == EPI_RELU_BF16) {
          p.Ob[(long)m * p.N + n] = __float2bfloat16(fmaxf(v + p.bias[n], 0.f));
        }
      }
    }
  }
}

// ---------------- fused flash attention ----------------
// 1D grid of 384: qt = blk/48, bh = blk%48 -> the 8 q-tile blocks sharing one
// head's K/V are spaced 48 apart (48%8==0) -> same XCD -> K/V stays in that
// XCD's L2 (6 heads x 256KB = 1.5MB < 4MB).
// 256 threads = 4 waves x 32 q-rows. K/V double-buffered in LDS.
__global__ __launch_bounds__(256)
void attn_flash(const bf16* __restrict__ qkv, bf16* __restrict__ cc) {
  __shared__ __align__(16) bf16 Ks[2][64 * 64], Vs[2][64 * 64];
  __shared__ __align__(16) bf16 Pl[4][32 * 76];
  const int tid = threadIdx.x, lane = tid & 63, wid = tid >> 6;
  const int lr = lane & 15, lg = lane >> 4;
  const int blk = blockIdx.x;
  const int qt = blk / 48, bh = blk - qt * 48;
  const int b = bh / 12, h = bh - b * 12;
  const long qb = (long)bh << 16;
  const bf16* Qg = qkv + qb;
  const bf16* Kg = qkv + 3145728 + qb;
  const bf16* Vg = qkv + 6291456 + qb;
  const int q0 = qt * 128 + wid * 32;
  const int lrow8 = lane >> 3, lcol8 = (lane & 7) * 8;

  v8s aq[2][2];
#pragma unroll
  for (int mi = 0; mi < 2; ++mi)
#pragma unroll
    for (int ks = 0; ks < 2; ++ks)
      aq[mi][ks] = *(const v8s*)&Qg[(long)(q0 + mi * 16 + lr) * 64 + ks * 32 + lg * 8];

  float mrow[2][4], lrow_[2][4];
  f32x4 acc[2][4] = {};
#pragma unroll
  for (int mi = 0; mi < 2; ++mi)
#pragma unroll
    for (int r = 0; r < 4; ++r) { mrow[mi][r] = -1e30f; lrow_[mi][r] = 0.f; }
  bf16* myP = &Pl[wid][0];

  auto stageKV = [&](int buf, int kt) {
#pragma unroll
    for (int i = 0; i < 2; ++i) {
      int c = wid + i * 4;
      g2lds16(&Kg[(long)(kt + c * 8 + lrow8) * 64 + lcol8], &Ks[buf][c << 9]);
      g2lds16(&Vg[((long)(c * 8 + lrow8) << 10) + kt + lcol8], &Vs[buf][c << 9]);
    }
  };

  stageKV(0, 0);
  __syncthreads();  // buf0 staged (vmcnt drained at barrier)

  for (int it = 0; it < 16; ++it) {
    const int cur = it & 1;
    if (it + 1 < 16) stageKV(cur ^ 1, (it + 1) * 64);
    const bf16* Kc = &Ks[cur][0];
    const bf16* Vc = &Vs[cur][0];

    // S = Q K^T
    f32x4 s[2][4] = {};
#pragma unroll
    for (int ks = 0; ks < 2; ++ks) {
      v8s bk[4];
#pragma unroll
      for (int ni = 0; ni < 4; ++ni)
        bk[ni] = *(const v8s*)&Kc[(ni * 16 + lr) * 64 + ks * 32 + lg * 8];
#pragma unroll
      for (int mi = 0; mi < 2; ++mi)
#pragma unroll
        for (int ni = 0; ni < 4; ++ni)
          s[mi][ni] = __builtin_amdgcn_mfma_f32_16x16x32_bf16(aq[mi][ks], bk[ni], s[mi][ni], 0, 0, 0);
    }

    // online softmax; write P (bf16) to per-wave LDS
#pragma unroll
    for (int mi = 0; mi < 2; ++mi) {
#pragma unroll
      for (int r = 0; r < 4; ++r) {
        float tm = fmaxf(fmaxf(s[mi][0][r], s[mi][1][r]), fmaxf(s[mi][2][r], s[mi][3][r]));
#pragma unroll
        for (int o = 1; o < 16; o <<= 1) tm = fmaxf(tm, __shfl_xor(tm, o));
        float mn = fmaxf(mrow[mi][r], tm);
        float al = __expf(mrow[mi][r] - mn);
        mrow[mi][r] = mn;
        float ps = 0.f;
        const int prow = (mi * 16 + lg * 4 + r) * 76;
#pragma unroll
        for (int ni = 0; ni < 4; ++ni) {
          float pv = __expf(s[mi][ni][r] - mn);
          myP[prow + ni * 16 + lr] = __float2bfloat16(pv);
          ps += pv;
        }
#pragma unroll
        for (int o = 1; o < 16; o <<= 1) ps += __shfl_xor(ps, o);
        lrow_[mi][r] = lrow_[mi][r] * al + ps;
#pragma unroll
        for (int ni = 0; ni < 4; ++ni) acc[mi][ni][r] *= al;
      }
    }

    // O += P * V  (V d-major -> contiguous B-frags)
#pragma unroll
    for (int ks = 0; ks < 2; ++ks) {
      v8s pa[2], bv[4];
#pragma unroll
      for (int mi = 0; mi < 2; ++mi)
        pa[mi] = *(const v8s*)&myP[(mi * 16 + lr) * 76 + ks * 32 + lg * 8];
#pragma unroll
      for (int ni = 0; ni < 4; ++ni)
        bv[ni] = *(const v8s*)&Vc[(ni * 16 + lr) * 64 + ks * 32 + lg * 8];
#pragma unroll
      for (int mi = 0; mi < 2; ++mi)
#pragma unroll
        for (int ni = 0; ni < 4; ++ni)
          acc[mi][ni] = __builtin_amdgcn_mfma_f32_16x16x32_bf16(pa[mi], bv[ni], acc[mi][ni], 0, 0, 0);
    }
    __syncthreads();  // all waves done with cur; next buffer fully staged
  }

  // epilogue: normalize and write concat layout [b*1024+t][h*64+d]
#pragma unroll
  for (int mi = 0; mi < 2; ++mi)
#pragma unroll
    for (int ni = 0; ni < 4; ++ni)
#pragma unroll
      for (int r = 0; r < 4; ++r) {
        int row = q0 + mi * 16 + lg * 4 + r;
        cc[((long)(b << 10) + row) * 768 + h * 64 + ni * 16 + lr] =
            __float2bfloat16(acc[mi][ni][r] / lrow_[mi][r]);
      }
}

// ---------------- residual + LayerNorm (row=768) ----------------
__global__ __launch_bounds__(256)
void ln_resid(const float* __restrict__ xin, const float* __restrict__ add,
              const float* __restrict__ g, const float* __restrict__ bb,
              float* __restrict__ xo, bf16* __restrict__ xbo) {
  __shared__ float red[4];
  long row = blockIdx.x;
  const float* xr = xin + row * 768;
  const float* ar = add + row * 768;
  int tid = threadIdx.x;
  float v0 = xr[tid] + ar[tid];
  float v1 = xr[tid + 256] + ar[tid + 256];
  float v2 = xr[tid + 512] + ar[tid + 512];
  float mean = block_sum(v0 + v1 + v2, red, tid) * (1.f / 768.f);
  v0 -= mean; v1 -= mean; v2 -= mean;
  float var = block_sum(v0 * v0 + v1 * v1 + v2 * v2, red, tid) * (1.f / 768.f);
  float rs = rsqrtf(var + 1e-5f);
  float o0 = v0 * rs * g[tid]       + bb[tid];
  float o1 = v1 * rs * g[tid + 256] + bb[tid + 256];
  float o2 = v2 * rs * g[tid + 512] + bb[tid + 512];
  float* xro = xo + row * 768;
  bf16*  xbr = xbo + row * 768;
  xro[tid] = o0; xro[tid + 256] = o1; xro[tid + 512] = o2;
  xbr[tid] = __float2bfloat16(o0);
  xbr[tid + 256] = __float2bfloat16(o1);
  xbr[tid + 512] = __float2bfloat16(o2);
}

// ---------------- classifier head ----------------
__global__ __launch_bounds__(256)
void head_cls(const float* __restrict__ x,
              const float* __restrict__ lnpg, const float* __restrict__ lnpb,
              const float* __restrict__ hlng, const float* __restrict__ hlnb,
              float* __restrict__ cls) {
  __shared__ float red[4];
  int b = blockIdx.x, tid = threadIdx.x;
  const float* xr = x + (long)b * 1024 * 768;  // row t=0
  float v0 = xr[tid], v1 = xr[tid + 256], v2 = xr[tid + 512];
  float s = block_sum(v0 + v1 + v2, red, tid) * (1.f / 768.f);
  v0 -= s; v1 -= s; v2 -= s;
  float q = block_sum(v0 * v0 + v1 * v1 + v2 * v2, red, tid) * (1.f / 768.f);
  float r = rsqrtf(q + 1e-5f);
  v0 = v0 * r * lnpg[tid]       + lnpb[tid];
  v1 = v1 * r * lnpg[tid + 256] + lnpb[tid + 256];
  v2 = v2 * r * lnpg[tid + 512] + lnpb[tid + 512];
  s = block_sum(v0 + v1 + v2, red, tid) * (1.f / 768.f);
  v0 -= s; v1 -= s; v2 -= s;
  q = block_sum(v0 * v0 + v1 * v1 + v2 * v2, red, tid) * (1.f / 768.f);
  r = rsqrtf(q + 1e-5f);
  cls[b * 768 + tid]       = v0 * r * hlng[tid]       + hlnb[tid];
  cls[b * 768 + tid + 256] = v1 * r * hlng[tid + 256] + hlnb[tid + 256];
  cls[b * 768 + tid + 512] = v2 * r * hlng[tid + 512] + hlnb[tid + 512];
}

// split-K GEMV stage A
__global__ __launch_bounds__(256)
void mlp_part(const float* __restrict__ in, const float* __restrict__ wmat,
              float* __restrict__ part, int IN, int OUTP, int ET) {
  __shared__ float cin[4][96];
  __shared__ float red[8][32][16];
  int tid = threadIdx.x;
  int tx = tid & 31, ty = tid >> 5;
  int e0 = blockIdx.y * ET;
  for (int i = tid; i < 4 * ET; i += 256) {
    int b = i / ET, el = i - b * ET;
    cin[b][el] = in[b * IN + e0 + el];
  }
  __syncthreads();
  f32x4 acc[4] = {};
  const float* wp = wmat + (long)e0 * OUTP + (blockIdx.x * 32 + tx) * 4;
  const int iters = ET >> 3;
  for (int i = 0; i < iters; ++i) {
    int el = ty + i * 8;
    f32x4 w = *(const f32x4*)(wp + (long)el * OUTP);
#pragma unroll
    for (int b = 0; b < 4; ++b) acc[b] += cin[b][el] * w;
  }
#pragma unroll
  for (int b = 0; b < 4; ++b) *(f32x4*)&red[ty][tx][b * 4] = acc[b];
  __syncthreads();
  if (tid < 128) {
    int rx = tid & 31, b = tid >> 5;
    f32x4 s = {};
#pragma unroll
    for (int t = 0; t < 8; ++t) s += *(const f32x4*)&red[t][rx][b * 4];
    *(f32x4*)&part[((long)blockIdx.y * 4 + b) * OUTP + (blockIdx.x * 32 + rx) * 4] = s;
  }
}

__global__ __launch_bounds__(256)
void mlp_reduce(const float* __restrict__ part, const float* __restrict__ bias,
                float* __restrict__ out, int OUTP, int S, int relu) {
  int idx = blockIdx.x * 256 + threadIdx.x;
  int b = idx / OUTP, j = idx - b * OUTP;
  float s = bias[j];
  for (int t = 0; t < S; ++t) s += part[((long)t * 4 + b) * OUTP + j];
  out[idx] = relu ? fmaxf(s, 0.f) : s;
}

// C=527 logits in [4][640] padded rows
__global__ __launch_bounds__(256)
void head_softmax(const float* __restrict__ lg, float* __restrict__ out) {
  __shared__ float red[4];
  int b = blockIdx.x, tid = threadIdx.x;
  const float* r = lg + (long)b * 640;
  float v0 = r[tid];
  float v1 = tid + 256 < 527 ? r[tid + 256] : -1e30f;
  float v2 = tid + 512 < 527 ? r[tid + 512] : -1e30f;
  float mx = block_max(fmaxf(v0, fmaxf(v1, v2)), red, tid);
  float e0 = __expf(v0 - mx);
  float e1 = tid + 256 < 527 ? __expf(v1 - mx) : 0.f;
  float e2 = tid + 512 < 527 ? __expf(v2 - mx) : 0.f;
  float sm = block_sum(e0 + e1 + e2, red, tid);
  float inv = 1.f / sm;
  out[(long)b * 527 + tid] = e0 * inv;
  if (tid + 256 < 527) out[(long)b * 527 + tid + 256] = e1 * inv;
  if (tid + 512 < 527) out[(long)b * 527 + tid + 512] = e2 * inv;
}

// ---------------- launcher ----------------
extern "C" void kernel_launch(void* const* d_in, const int* in_sizes, int n_in,
                              void* d_out, int out_size, void* d_ws, size_t ws_size,
                              hipStream_t stream) {
  const float* x_in    = (const float*)d_in[0];
  const float* conv1_w = (const float*)d_in[1];
  const float* conv1_b = (const float*)d_in[2];
  const float* conv2_w = (const float*)d_in[3];
  const float* conv2_b = (const float*)d_in[4];
  const float* pos_emb = (const float*)d_in[5];
  const float* ln1_g   = (const float*)d_in[6];
  const float* ln1_b   = (const float*)d_in[7];
  const float* wq      = (const float*)d_in[8];
  const float* bq      = (const float*)d_in[9];
  const float* wk      = (const float*)d_in[10];
  const float* bk      = (const float*)d_in[11];
  const float* wv      = (const float*)d_in[12];
  const float* bv      = (const float*)d_in[13];
  const float* wo      = (const float*)d_in[14];
  const float* bo      = (const float*)d_in[15];
  const float* w1      = (const float*)d_in[16];
  const float* b1      = (const float*)d_in[17];
  const float* w2      = (const float*)d_in[18];
  const float* b2      = (const float*)d_in[19];
  const float* ln2_g   = (const float*)d_in[20];
  const float* ln2_b   = (const float*)d_in[21];
  const float* lnp_g   = (const float*)d_in[22];
  const float* lnp_b   = (const float*)d_in[23];
  const float* hln_g   = (const float*)d_in[24];
  const float* hln_b   = (const float*)d_in[25];
  const float* hw1     = (const float*)d_in[26];
  const float* hb1     = (const float*)d_in[27];
  const float* hw2     = (const float*)d_in[28];
  const float* hb2     = (const float*)d_in[29];

  // workspace layout
  char* w = (char*)d_ws;
  bf16*  wqkvT = (bf16*)(w);                      // 6*2304*768 bf16
  bf16*  woT   = (bf16*)(w + 21233664);           // 6*768*768
  bf16*  w1T   = (bf16*)(w + 28311552);           // 6*3072*768
  bf16*  w2T   = (bf16*)(w + 56623104);           // 6*768*3072
  bf16*  wc1T  = (bf16*)(w + 84934656);           // 768*256
  bf16*  wc2T  = (bf16*)(w + 85327872);           // 768*2304
  float* bqkv  = (float*)(w + 88866816);          // 6*2304 f32
  float* Xf    = (float*)(w + 88922112);          // 4096*768 f32
  bf16*  Xb    = (bf16*)(w + 101505024);          // 4096*768
  bf16*  qkv   = (bf16*)(w + 107796480);          // 3*4096*768 (q t-major, k t-major, v d-major)
  bf16*  CC    = (bf16*)(w + 126670848);          // 4096*768
  float* ATTN  = (float*)(w + 132962304);         // 4096*768 f32
  char*  BIG   = w + 145545216;                   // 50,331,648 shared region
  bf16*  A1  = (bf16*)(BIG);                      // 8192*256   (conv phase)
  bf16*  Y1G = (bf16*)(BIG + 4194304);            // 8192*768   (conv phase)
  bf16*  A2  = (bf16*)(BIG + 16777216);           // 4096*2304  (conv phase)
  bf16*  Hh  = (bf16*)(BIG);                      // 4096*3072  (ffn phase)
  float* FFN = (float*)(BIG + 25165824);          // 4096*768 f32 (ffn phase)
  // head phase (aliases, used only after last FFN)
  float* CLS  = (float*)(BIG);                    // 4*768
  float* HID  = (float*)(BIG + 16384);            // 4*3072
  float* LGT  = (float*)(BIG + 81920);            // 4*640
  float* PT1  = (float*)(BIG + 131072);           // 16*4*3072
  float* PT2  = (float*)(BIG + 1048576);          // 32*4*640
  float* HB2P = (float*)(BIG + 1572864);          // 640
  float* HW2P = (float*)(BIG + 1605632);          // 3072*640

  // ---- weight prep ----
  tconv<<<dim3(2, 24, 72), 256, 0, stream>>>(wq, wqkvT,            768, 64,   49152L, 1769472L, 49152L, 12);
  tconv<<<dim3(2, 24, 72), 256, 0, stream>>>(wk, wqkvT + 589824,   768, 64,   49152L, 1769472L, 49152L, 12);
  tconv<<<dim3(2, 24, 72), 256, 0, stream>>>(wv, wqkvT + 1179648,  768, 64,   49152L, 1769472L, 49152L, 12);
  tconv<<<dim3(24, 24, 6), 256, 0, stream>>>(wo, woT,              768, 768,  589824L, 589824L, 0L, 1);
  tconv<<<dim3(96, 24, 6), 256, 0, stream>>>(w1, w1T,              768, 3072, 2359296L, 2359296L, 0L, 1);
  tconv<<<dim3(24, 96, 6), 256, 0, stream>>>(w2, w2T,              3072, 768, 2359296L, 2359296L, 0L, 1);
  prep_cw<<<768,  256, 0, stream>>>(conv1_w, wc1T, 80, 256);
  prep_cw<<<6912, 256, 0, stream>>>(conv2_w, wc2T, 768, 2304);
  prep_bias<<<54, 256, 0, stream>>>(bq, bk, bv, bqkv);

  // ---- convs ----
  im2col1<<<8192, 256, 0, stream>>>(x_in, A1);
  { GP p{}; p.A = A1; p.B = wc1T; p.bias = conv1_b; p.Ob = Y1G;
    p.M = 8192; p.N = 768; p.K = 256;
    gemm_bt<128,64,2,2,EPI_GELU_BF16><<<dim3(64,12,1),256,0,stream>>>(p); }
  im2col2<<<36864, 256, 0, stream>>>(Y1G, A2);
  { GP p{}; p.A = A2; p.B = wc2T; p.bias = conv2_b; p.Of = Xf; p.Ob = Xb; p.aux = pos_emb;
    p.M = 4096; p.N = 768; p.K = 2304;
    gemm_bt<128,64,2,2,EPI_CONV2><<<dim3(32,12,1),256,0,stream>>>(p); }

  // ---- transformer layers ----
  for (int l = 0; l < 6; ++l) {
    { GP p{}; p.A = Xb; p.B = wqkvT + (long)l * 1769472; p.bias = bqkv + l * 2304;
      p.Ob = qkv; p.M = 4096; p.N = 2304; p.K = 768;
      gemm_bt<128,128,2,2,EPI_QKV><<<dim3(32,18,1),256,0,stream>>>(p); }
    attn_flash<<<384, 256, 0, stream>>>(qkv, CC);
    { GP p{}; p.A = CC; p.B = woT + (long)l * 589824; p.bias = bo + l * 768; p.Of = ATTN;
      p.M = 4096; p.N = 768; p.K = 768;
      gemm_bt<128,64,2,2,EPI_BIAS_F32><<<dim3(32,12,1),256,0,stream>>>(p); }
    ln_resid<<<4096, 256, 0, stream>>>(Xf, ATTN, ln1_g + l * 768, ln1_b + l * 768, Xf, Xb);
    { GP p{}; p.A = Xb; p.B = w1T + (long)l * 2359296; p.bias = b1 + l * 3072; p.Ob = Hh;
      p.M = 4096; p.N = 3072; p.K = 768;
      gemm_bt<128,128,2,2,EPI_RELU_BF16><<<dim3(32,24,1),256,0,stream>>>(p); }
    { GP p{}; p.A = Hh; p.B = w2T + (long)l * 2359296; p.bias = b2 + l * 768; p.Of = FFN;
      p.M = 4096; p.N = 768; p.K = 3072;
      gemm_bt<128,64,2,2,EPI_BIAS_F32><<<dim3(32,12,1),256,0,stream>>>(p); }
    ln_resid<<<4096, 256, 0, stream>>>(Xf, FFN, ln2_g + l * 768, ln2_b + l * 768, Xf, Xb);
  }

  // ---- head ----
  head_cls<<<4, 256, 0, stream>>>(Xf, lnp_g, lnp_b, hln_g, hln_b, CLS);
  prep_hw2<<<7680, 256, 0, stream>>>(hw2, hb2, HW2P, HB2P);
  mlp_part<<<dim3(24, 16), 256, 0, stream>>>(CLS, hw1, PT1, 768, 3072, 48);
  mlp_reduce<<<48, 256, 0, stream>>>(PT1, hb1, HID, 3072, 16, 1);
  mlp_part<<<dim3(5, 32), 256, 0, stream>>>(HID, HW2P, PT2, 3072, 640, 96);
  mlp_reduce<<<10, 256, 0, stream>>>(PT2, HB2P, LGT, 640, 32, 0);
  head_softmax<<<4, 256, 0, stream>>>(LGT, (float*)d_out);
}